// Round 12
// baseline (322.077 us; speedup 1.0000x reference)
//
#include <hip/hip_runtime.h>
#include <math.h>

#define NNODES 100000
#define NEDGES 1600000
#define DD 64
#define EPS 1e-8f

#define NBUCK 1024
#define BW 98
#define BIN_BLOCKS 512
#define BIN_CHUNK ((NEDGES + BIN_BLOCKS - 1) / BIN_BLOCKS)  // 3125
#define BIN_CAP 8
#define SORT_CAP 4096
#define NTILES (NNODES / 16)   // 6250, exact
#define CAP4 512
#define TSTR 68                // LDS transpose row stride (floats)

typedef unsigned short us8 __attribute__((ext_vector_type(8)));
typedef short short8 __attribute__((ext_vector_type(8)));
typedef float f32x4 __attribute__((ext_vector_type(4)));

__device__ __forceinline__ float wave_sum(float v) {
    #pragma unroll
    for (int off = 32; off; off >>= 1) v += __shfl_xor(v, off, 64);
    return v;
}

__device__ __forceinline__ float hinner(float u, float v, float sgn) {
    return wave_sum(sgn * u * v);
}

__device__ __forceinline__ float cross_ratio(float r0, float r1, float r2, float r3, float sgn) {
    float A = hinner(r0, r2, sgn);
    float B = hinner(r1, r3, sgn);
    float C = hinner(r0, r3, sgn);
    float Dv = hinner(r1, r2, sgn);
    return (A * B) / (C * Dv + EPS);
}

__device__ __forceinline__ float restore_scale(float cr_i, float cr_c) {
    float ratio = cr_i / (cr_c + EPS);
    bool cond = (!__builtin_isnan(cr_c)) && (!__builtin_isnan(cr_i)) &&
                (fabsf(cr_c) > EPS) && (fabsf(cr_i) > EPS) && (ratio > EPS);
    float s = 1.0f;
    if (cond) {
        s = sqrtf(fabsf(ratio));
        if (!__builtin_isfinite(s)) s = 1.0f;
    }
    return s;
}

__device__ __forceinline__ unsigned short f2bf(float f) {
    unsigned u = __float_as_uint(f);
    unsigned r = (u + 0x7fffu + ((u >> 16) & 1u)) >> 16;
    return (unsigned short)r;
}

__device__ __forceinline__ float bf2f(unsigned short b) {
    return __uint_as_float(((unsigned)b) << 16);
}

__device__ __forceinline__ float bcast(float v, int lane) {
    return __int_as_float(__builtin_amdgcn_readlane(__float_as_int(v), lane));
}

__device__ __forceinline__ int ibcast(int v, int lane) {
    return __builtin_amdgcn_readlane(v, lane);
}

// load one weight matrix as split-bf16 B fragments in VGPRs (used by k_l0h)
__device__ __forceinline__ void load_bfrags(const float* __restrict__ W, int lane,
                                            short8 bhi[4][2], short8 blo[4][2]) {
    int c = lane & 15, q = lane >> 4;
    #pragma unroll
    for (int t = 0; t < 4; t++)
        #pragma unroll
        for (int h = 0; h < 2; h++) {
            short8 hi8, lo8;
            #pragma unroll
            for (int j = 0; j < 8; j++) {
                float w = W[(h * 32 + q * 8 + j) * DD + t * 16 + c];
                unsigned short hb = f2bf(w);
                float r = w - bf2f(hb);
                hi8[j] = (short)hb;
                lo8[j] = (short)f2bf(r);
            }
            bhi[t][h] = hi8;
            blo[t][h] = lo8;
        }
}

__device__ __forceinline__ void build_a8(const float av[8], short8& hi, short8& lo) {
    short8 h8, l8;
    #pragma unroll
    for (int j = 0; j < 8; j++) {
        unsigned short hb = f2bf(av[j]);
        float r = av[j] - bf2f(hb);
        h8[j] = (short)hb;
        l8[j] = (short)f2bf(r);
    }
    hi = h8;
    lo = l8;
}

__device__ __forceinline__ void build_a(const float* p, short8& hi, short8& lo) {
    float4 f0 = *(const float4*)p;
    float4 f1 = *(const float4*)(p + 4);
    float av[8] = {f0.x, f0.y, f0.z, f0.w, f1.x, f1.y, f1.z, f1.w};
    build_a8(av, hi, lo);
}

#define MFMA3R(cacc, ahi, alo, BH, BL, t, h)                                     \
    cacc = __builtin_amdgcn_mfma_f32_16x16x32_bf16(ahi, BH[t][h], cacc, 0, 0, 0); \
    cacc = __builtin_amdgcn_mfma_f32_16x16x32_bf16(alo, BH[t][h], cacc, 0, 0, 0); \
    cacc = __builtin_amdgcn_mfma_f32_16x16x32_bf16(ahi, BL[t][h], cacc, 0, 0, 0);

// fused: blocks [0,512) bucket-histogram; blocks [512,1536) layer0 MFMA.
__global__ __launch_bounds__(256, 3) void k_l0h(const float* __restrict__ x,
                                                const float* __restrict__ W0,
                                                const float* __restrict__ b0,
                                                unsigned short* __restrict__ h0b,
                                                const int* __restrict__ ei,
                                                int* __restrict__ bhist) {
    __shared__ int h[NBUCK];
    if (blockIdx.x < 512) {
        for (int i = threadIdx.x; i < NBUCK; i += 256) h[i] = 0;
        __syncthreads();
        int tid = blockIdx.x * 256 + threadIdx.x;
        int stride = 512 * 256;
        for (int e = tid; e < NEDGES; e += stride)
            atomicAdd(&h[(unsigned)ei[NEDGES + e] / BW], 1);
        __syncthreads();
        for (int i = threadIdx.x; i < NBUCK; i += 256)
            if (h[i]) atomicAdd(&bhist[i], h[i]);
        return;
    }
    int bid = blockIdx.x - 512;
    int lane = threadIdx.x & 63;
    int c = lane & 15, q = lane >> 4;
    short8 bhi[4][2], blo[4][2];
    load_bfrags(W0, lane, bhi, blo);
    float badd[4];
    #pragma unroll
    for (int t = 0; t < 4; t++) badd[t] = b0[t * 16 + c];
    int wid = (bid * 256 + threadIdx.x) >> 6;
    int nw = (1024 * 256) >> 6;
    for (int tile = wid; tile < NTILES; tile += nw) {
        int R = tile * 16;
        f32x4 cc[4] = {{0, 0, 0, 0}, {0, 0, 0, 0}, {0, 0, 0, 0}, {0, 0, 0, 0}};
        #pragma unroll
        for (int hh = 0; hh < 2; hh++) {
            short8 ahi, alo;
            build_a(x + ((size_t)(R + c) << 6) + hh * 32 + q * 8, ahi, alo);
            #pragma unroll
            for (int t = 0; t < 4; t++) { MFMA3R(cc[t], ahi, alo, bhi, blo, t, hh); }
        }
        float ss[4];
        #pragma unroll
        for (int r = 0; r < 4; r++) {
            #pragma unroll
            for (int t = 0; t < 4; t++) cc[t][r] += badd[t];
            ss[r] = cc[0][r] * cc[0][r] + cc[1][r] * cc[1][r] +
                    cc[2][r] * cc[2][r] + cc[3][r] * cc[3][r];
        }
        #pragma unroll
        for (int off = 1; off <= 8; off <<= 1) {
            #pragma unroll
            for (int r = 0; r < 4; r++) ss[r] += __shfl_xor(ss[r], off, 64);
        }
        #pragma unroll
        for (int r = 0; r < 4; r++) {
            float sc = 1.0f / (sqrtf(ss[r]) + EPS);
            int row = R + q * 4 + r;
            #pragma unroll
            for (int t = 0; t < 4; t++)
                h0b[(size_t)row * DD + t * 16 + c] = f2bf(cc[t][r] * sc);
        }
    }
}

// single block: exclusive scan of 1024 bucket counts -> bstart, gcur; init misc.
__global__ __launch_bounds__(NBUCK) void k_scan1024(const int* __restrict__ bhist,
                                                    int* __restrict__ bstart,
                                                    int* __restrict__ gcur,
                                                    int* __restrict__ scratch_cur,
                                                    int* __restrict__ row_ptr) {
    __shared__ int s[NBUCK];
    int t = threadIdx.x;
    int v = bhist[t];
    s[t] = v;
    __syncthreads();
    for (int off = 1; off < NBUCK; off <<= 1) {
        int u = (t >= off) ? s[t - off] : 0;
        __syncthreads();
        s[t] += u;
        __syncthreads();
    }
    bstart[t] = s[t] - v;
    gcur[t] = s[t] - v;
    if (t == 0) {
        scratch_cur[0] = 0;
        row_ptr[NNODES] = NEDGES;
    }
}

// bin edges into per-bucket dense runs; also collect rows 0..3 neighbor lists.
__global__ __launch_bounds__(256) void k_bin(const int* __restrict__ ei,
                                             int* __restrict__ gcur,
                                             unsigned* __restrict__ colpack,
                                             int* __restrict__ cnt4,
                                             int* __restrict__ list4) {
    __shared__ unsigned stag[NBUCK * BIN_CAP];
    __shared__ int lcnt[NBUCK];
    int t = threadIdx.x;
    for (int i = t; i < NBUCK; i += 256) lcnt[i] = 0;
    __syncthreads();
    int lo = blockIdx.x * BIN_CHUNK;
    int hi = lo + BIN_CHUNK; if (hi > NEDGES) hi = NEDGES;
    for (int e = lo + t; e < hi; e += 256) {
        int d = ei[NEDGES + e];
        int s = ei[e];
        if ((unsigned)d < 4u) {
            int p = atomicAdd(&cnt4[d], 1);
            if (p < CAP4) list4[d * CAP4 + p] = s;
        }
        unsigned b = (unsigned)d / BW;
        unsigned dl = (unsigned)d - b * BW;
        unsigned pk = ((unsigned)s << 8) | dl;
        int slot = atomicAdd(&lcnt[b], 1);
        if (slot < BIN_CAP) {
            stag[b * BIN_CAP + slot] = pk;
        } else {
            colpack[atomicAdd(&gcur[b], 1)] = pk;
        }
    }
    __syncthreads();
    for (int b = t; b < NBUCK; b += 256) {
        int cnt = lcnt[b];
        if (cnt > BIN_CAP) cnt = BIN_CAP;
        if (cnt > 0) {
            int base = atomicAdd(&gcur[b], cnt);
            for (int i = 0; i < cnt; i++)
                colpack[base + i] = stag[b * BIN_CAP + i];
        }
    }
}

// blocks [0,NBUCK): per-bucket degree count + row_ptr write + counting sort.
// block NBUCK: head — rows 0..3 full pipeline in fp32 -> scal.
__global__ __launch_bounds__(256, 4) void k_sortDH(unsigned* __restrict__ colpack,
                                                   const int* __restrict__ bstart,
                                                   const int* __restrict__ bhist,
                                                   int* __restrict__ row_ptr,
                                                   int* __restrict__ scratch,
                                                   int* __restrict__ scratch_cur,
                                                   const float* __restrict__ x,
                                                   const float* __restrict__ W0,
                                                   const float* __restrict__ b0,
                                                   const int* __restrict__ cnt4,
                                                   const int* __restrict__ list4,
                                                   const float* __restrict__ Wm,
                                                   const float* __restrict__ bm,
                                                   const float* __restrict__ W1,
                                                   const float* __restrict__ b1,
                                                   float* __restrict__ scal) {
    __shared__ int cnt[BW];
    __shared__ int pre[BW];
    __shared__ float hs[4][DD];
    __shared__ float h2s[4][DD];
    __shared__ float frs[4][DD];
    int t = threadIdx.x;
    if (blockIdx.x == NBUCK) {
        int lane = t & 63;
        int w = t >> 6;
        float sgn = (lane == 63) ? -1.0f : 1.0f;
        float w0[DD];
        #pragma unroll
        for (int k = 0; k < DD; k++) w0[k] = W0[k * DD + lane];
        float b0v = b0[lane];
        auto h0row = [&](int r) -> float {
            float xv = x[(size_t)r * DD + lane];
            float acc = b0v;
            #pragma unroll
            for (int k = 0; k < DD; k++)
                acc = fmaf(bcast(xv, k), w0[k], acc);
            float n = sqrtf(wave_sum(acc * acc));
            return acc / (n + EPS);
        };
        hs[w][lane] = h0row(w);
        int full = cnt4[w];
        int cl = full; if (cl > CAP4) cl = CAP4;
        float sum = 0.0f;
        for (int i = 0; i < cl; i++) sum += h0row(list4[w * CAP4 + i]);
        float av = sum / fmaxf((float)full, 1.0f);
        float acc = bm[lane];
        #pragma unroll
        for (int k = 0; k < DD; k++)
            acc = fmaf(bcast(av, k), Wm[k * DD + lane], acc);
        float n = sqrtf(wave_sum(acc * acc));
        h2s[w][lane] = acc / (n + EPS);
        __syncthreads();
        float cr_init = cross_ratio(x[lane], x[DD + lane], x[2 * DD + lane], x[3 * DD + lane], sgn);
        float cr0 = cross_ratio(hs[0][lane], hs[1][lane], hs[2][lane], hs[3][lane], sgn);
        float cr_cur = cross_ratio(h2s[0][lane], h2s[1][lane], h2s[2][lane], h2s[3][lane], sgn);
        float s1 = restore_scale(cr0, cr_cur);
        float hv = h2s[w][lane] * s1;
        float acc2 = b1[lane];
        #pragma unroll
        for (int k = 0; k < DD; k++)
            acc2 = fmaf(bcast(hv, k), W1[k * DD + lane], acc2);
        n = sqrtf(wave_sum(acc2 * acc2));
        frs[w][lane] = fmaxf(acc2 / (n + EPS), 0.0f);
        __syncthreads();
        if (w == 0) {
            float cr2 = cross_ratio(frs[0][lane], frs[1][lane], frs[2][lane], frs[3][lane], sgn);
            float s2 = restore_scale(cr_init, cr2);
            if (lane == 0) { scal[0] = s1; scal[1] = s2; }
        }
        return;
    }
    int b = blockIdx.x;
    int nlo = b * BW; if (nlo > NNODES) nlo = NNODES;
    int nhi = nlo + BW; if (nhi > NNODES) nhi = NNODES;
    int base = bstart[b];
    int n = bhist[b];
    for (int i = t; i < BW; i += 256) cnt[i] = 0;
    __syncthreads();
    if (n <= SORT_CAP) {
        unsigned ent[SORT_CAP / 256];
        int c = 0;
        for (int i = t; i < n; i += 256) {
            ent[c] = colpack[base + i];
            atomicAdd(&cnt[ent[c] & 255u], 1);
            c++;
        }
        __syncthreads();
        if (t == 0) {
            int s = 0;
            for (int i = 0; i < BW; i++) { pre[i] = s; s += cnt[i]; }
        }
        __syncthreads();
        for (int i = t; i < nhi - nlo; i += 256)
            row_ptr[nlo + i] = base + pre[i];
        for (int i = t; i < BW; i += 256) cnt[i] = pre[i];
        __syncthreads();
        for (int j = 0; j < c; j++) {
            int pos = atomicAdd(&cnt[ent[j] & 255u], 1);
            colpack[base + pos] = ent[j] >> 8;
        }
    } else {
        int sb = 0;
        if (t == 0) sb = atomicAdd(scratch_cur, n);
        sb = __shfl(sb, 0, 64);
        sb = __builtin_amdgcn_readfirstlane(sb);
        for (int i = t; i < n; i += 256) {
            unsigned pk = colpack[base + i];
            scratch[sb + i] = (int)pk;
            atomicAdd(&cnt[pk & 255u], 1);
        }
        __syncthreads();
        if (t == 0) {
            int s = 0;
            for (int i = 0; i < BW; i++) { pre[i] = s; s += cnt[i]; }
        }
        __syncthreads();
        for (int i = t; i < nhi - nlo; i += 256)
            row_ptr[nlo + i] = base + pre[i];
        for (int i = t; i < BW; i += 256) cnt[i] = pre[i];
        __syncthreads();
        for (int i = t; i < n; i += 256) {
            unsigned pk = (unsigned)scratch[sb + i];
            int p = atomicAdd(&cnt[pk & 255u], 1);
            colpack[base + p] = pk >> 8;
        }
    }
}

// fused gather + GEMM1 + GEMM2: per-wave 16-row tile.
// gather-mean each row into per-wave LDS A-tile -> GEMM1(Wm) -> normalize*s1 ->
// LDS transpose -> GEMM2(W1) -> relu*s2 -> store out. Weights in LDS (bf16 hi/lo).
__global__ __launch_bounds__(256) void k_aggG(const unsigned short* __restrict__ h0b,
                                              const int* __restrict__ row_ptr,
                                              const int* __restrict__ col,
                                              const float* __restrict__ Wm,
                                              const float* __restrict__ bm,
                                              const float* __restrict__ W1,
                                              const float* __restrict__ b1,
                                              const float* __restrict__ scal,
                                              float* __restrict__ out) {
    __shared__ short8 wmh[8][64], wml[8][64], w1h[8][64], w1l[8][64];  // 32 KB
    __shared__ float tsm[4][16 * TSTR];                                // 17.4 KB
    int tid = threadIdx.x;
    int wv = tid >> 6, lane = tid & 63;
    int c = lane & 15, q4 = lane >> 4;   // GEMM roles
    int q = lane & 7, g = lane >> 3;     // gather roles
    // cooperative weight prep: wave wv builds frags t=wv for both matrices
    {
        int t = wv;
        #pragma unroll
        for (int hh = 0; hh < 2; hh++) {
            short8 h8, l8;
            #pragma unroll
            for (int j = 0; j < 8; j++) {
                float w = Wm[(hh * 32 + q4 * 8 + j) * DD + t * 16 + c];
                unsigned short hb = f2bf(w);
                float r = w - bf2f(hb);
                h8[j] = (short)hb;
                l8[j] = (short)f2bf(r);
            }
            wmh[t * 2 + hh][lane] = h8;
            wml[t * 2 + hh][lane] = l8;
            #pragma unroll
            for (int j = 0; j < 8; j++) {
                float w = W1[(hh * 32 + q4 * 8 + j) * DD + t * 16 + c];
                unsigned short hb = f2bf(w);
                float r = w - bf2f(hb);
                h8[j] = (short)hb;
                l8[j] = (short)f2bf(r);
            }
            w1h[t * 2 + hh][lane] = h8;
            w1l[t * 2 + hh][lane] = l8;
        }
    }
    __syncthreads();
    float bmv[4], b1v[4];
    #pragma unroll
    for (int t = 0; t < 4; t++) { bmv[t] = bm[t * 16 + c]; b1v[t] = b1[t * 16 + c]; }
    float s1 = scal[0], s2 = scal[1];
    int wid = (blockIdx.x * 256 + tid) >> 6;
    int nw = (gridDim.x * 256) >> 6;
    for (int tile = wid; tile < NTILES; tile += nw) {
        int R = tile * 16;
        int rp = (lane <= 16) ? row_ptr[R + lane] : 0;
        // ---- gather 16 rows into tsm (A-layout rows) ----
        for (int r = 0; r < 16; r++) {
            int start = ibcast(rp, r), end = ibcast(rp, r + 1);
            float s[8] = {0, 0, 0, 0, 0, 0, 0, 0};
            for (int cb = start; cb < end; cb += 64) {
                int cv = (cb + lane < end) ? col[cb + lane] : 0;
                int m = end - cb; if (m > 64) m = 64;
                for (int j = 0; j < m; j += 8) {
                    int e = j + g;
                    bool val = e < m;
                    int esafe = val ? e : 0;
                    int src = __shfl(cv, esafe, 64);
                    us8 u = *(const us8*)(h0b + (size_t)src * DD + q * 8);
                    float f = val ? 1.0f : 0.0f;
                    #pragma unroll
                    for (int i = 0; i < 8; i++)
                        s[i] = fmaf(f, bf2f(u[i]), s[i]);
                }
            }
            #pragma unroll
            for (int i = 0; i < 8; i++) {
                s[i] += __shfl_xor(s[i], 8, 64);
                s[i] += __shfl_xor(s[i], 16, 64);
                s[i] += __shfl_xor(s[i], 32, 64);
            }
            if (g == 0) {
                float inv = 1.0f / fmaxf((float)(end - start), 1.0f);
                #pragma unroll
                for (int i = 0; i < 8; i++)
                    tsm[wv][r * TSTR + q * 8 + i] = s[i] * inv;
            }
        }
        // ---- GEMM1: A from tsm, B from LDS weights ----
        f32x4 cc[4] = {{0, 0, 0, 0}, {0, 0, 0, 0}, {0, 0, 0, 0}, {0, 0, 0, 0}};
        #pragma unroll
        for (int hh = 0; hh < 2; hh++) {
            float av[8];
            const float* p = &tsm[wv][c * TSTR + hh * 32 + q4 * 8];
            #pragma unroll
            for (int j = 0; j < 8; j++) av[j] = p[j];
            short8 ahi, alo;
            build_a8(av, ahi, alo);
            #pragma unroll
            for (int t = 0; t < 4; t++) {
                short8 bh = wmh[t * 2 + hh][lane];
                short8 bl = wml[t * 2 + hh][lane];
                cc[t] = __builtin_amdgcn_mfma_f32_16x16x32_bf16(ahi, bh, cc[t], 0, 0, 0);
                cc[t] = __builtin_amdgcn_mfma_f32_16x16x32_bf16(alo, bh, cc[t], 0, 0, 0);
                cc[t] = __builtin_amdgcn_mfma_f32_16x16x32_bf16(ahi, bl, cc[t], 0, 0, 0);
            }
        }
        float ss[4];
        #pragma unroll
        for (int r = 0; r < 4; r++) {
            #pragma unroll
            for (int t = 0; t < 4; t++) cc[t][r] += bmv[t];
            ss[r] = cc[0][r] * cc[0][r] + cc[1][r] * cc[1][r] +
                    cc[2][r] * cc[2][r] + cc[3][r] * cc[3][r];
        }
        #pragma unroll
        for (int off = 1; off <= 8; off <<= 1) {
            #pragma unroll
            for (int r = 0; r < 4; r++) ss[r] += __shfl_xor(ss[r], off, 64);
        }
        // H -> tsm (C-layout scatter), overwrites A
        #pragma unroll
        for (int r = 0; r < 4; r++) {
            float sc = s1 / (sqrtf(ss[r]) + EPS);
            #pragma unroll
            for (int t = 0; t < 4; t++)
                tsm[wv][(q4 * 4 + r) * TSTR + t * 16 + c] = cc[t][r] * sc;
        }
        // ---- GEMM2 ----
        f32x4 c2[4] = {{0, 0, 0, 0}, {0, 0, 0, 0}, {0, 0, 0, 0}, {0, 0, 0, 0}};
        #pragma unroll
        for (int hh = 0; hh < 2; hh++) {
            float av[8];
            const float* p = &tsm[wv][c * TSTR + hh * 32 + q4 * 8];
            #pragma unroll
            for (int j = 0; j < 8; j++) av[j] = p[j];
            short8 ahi, alo;
            build_a8(av, ahi, alo);
            #pragma unroll
            for (int t = 0; t < 4; t++) {
                short8 bh = w1h[t * 2 + hh][lane];
                short8 bl = w1l[t * 2 + hh][lane];
                c2[t] = __builtin_amdgcn_mfma_f32_16x16x32_bf16(ahi, bh, c2[t], 0, 0, 0);
                c2[t] = __builtin_amdgcn_mfma_f32_16x16x32_bf16(alo, bh, c2[t], 0, 0, 0);
                c2[t] = __builtin_amdgcn_mfma_f32_16x16x32_bf16(ahi, bl, c2[t], 0, 0, 0);
            }
        }
        #pragma unroll
        for (int r = 0; r < 4; r++) {
            #pragma unroll
            for (int t = 0; t < 4; t++) c2[t][r] += b1v[t];
            ss[r] = c2[0][r] * c2[0][r] + c2[1][r] * c2[1][r] +
                    c2[2][r] * c2[2][r] + c2[3][r] * c2[3][r];
        }
        #pragma unroll
        for (int off = 1; off <= 8; off <<= 1) {
            #pragma unroll
            for (int r = 0; r < 4; r++) ss[r] += __shfl_xor(ss[r], off, 64);
        }
        #pragma unroll
        for (int r = 0; r < 4; r++) {
            float sc = 1.0f / (sqrtf(ss[r]) + EPS);
            int row = R + q4 * 4 + r;
            #pragma unroll
            for (int t = 0; t < 4; t++)
                out[(size_t)row * DD + t * 16 + c] = fmaxf(c2[t][r] * sc, 0.0f) * s2;
        }
    }
}

extern "C" void kernel_launch(void* const* d_in, const int* in_sizes, int n_in,
                              void* d_out, int out_size, void* d_ws, size_t ws_size,
                              hipStream_t stream) {
    const float* x  = (const float*)d_in[0];
    const int*   ei = (const int*)d_in[1];
    const float* W0 = (const float*)d_in[2];
    const float* b0 = (const float*)d_in[3];
    const float* Wm = (const float*)d_in[4];
    const float* bm = (const float*)d_in[5];
    const float* W1 = (const float*)d_in[6];
    const float* b1 = (const float*)d_in[7];
    float* out = (float*)d_out;

    // ws layout (~20.0 MB)
    unsigned short* h0b = (unsigned short*)d_ws;                 // N*64 bf16 = 12.8 MB
    int* scratch = (int*)(h0b + (size_t)NNODES * DD);            // N (sort overflow scratch)
    int* row_ptr = scratch + NNODES;                             // N+1
    unsigned* colpack = (unsigned*)(row_ptr + NNODES + 1);       // E = 6.4 MB
    int* bhist  = (int*)(colpack + NEDGES);                      // 1024
    int* cnt4   = bhist + NBUCK;                                 // 4
    int* bstart = cnt4 + 4;                                      // 1024
    int* gcur   = bstart + NBUCK;                                // 1024
    int* scur   = gcur + NBUCK;                                  // 1
    int* list4  = scur + 1;                                      // 4*512
    float* scal = (float*)(list4 + 4 * CAP4);                    // 2

    (void)hipMemsetAsync(bhist, 0, (NBUCK + 4) * sizeof(int), stream);  // bhist + cnt4

    k_l0h     <<<1536, 256, 0, stream>>>(x, W0, b0, h0b, ei, bhist);
    k_scan1024<<<1, NBUCK, 0, stream>>>(bhist, bstart, gcur, scur, row_ptr);
    k_bin     <<<BIN_BLOCKS, 256, 0, stream>>>(ei, gcur, colpack, cnt4, list4);
    k_sortDH  <<<NBUCK + 1, 256, 0, stream>>>(colpack, bstart, bhist, row_ptr, scratch, scur,
                                              x, W0, b0, cnt4, list4, Wm, bm, W1, b1, scal);
    k_aggG    <<<2048, 256, 0, stream>>>(h0b, row_ptr, (const int*)colpack, Wm, bm, W1, b1, scal, out);
}

// Round 13
// 238.896 us; speedup vs baseline: 1.3482x; 1.3482x over previous
//
#include <hip/hip_runtime.h>
#include <math.h>

#define NNODES 100000
#define NEDGES 1600000
#define DD 64
#define EPS 1e-8f

#define NBUCK 1024
#define BW 98
#define BIN_BLOCKS 256
#define BIN_CHUNK ((NEDGES + BIN_BLOCKS - 1) / BIN_BLOCKS)  // 6250
#define BIN_CAP 16
#define SORT_CAP 4096
#define NTILES (NNODES / 16)   // 6250, exact
#define CAP4 512
#define TSTR 68                // LDS transpose row stride (floats)

typedef unsigned short us8 __attribute__((ext_vector_type(8)));
typedef short short8 __attribute__((ext_vector_type(8)));
typedef float f32x4 __attribute__((ext_vector_type(4)));

__device__ __forceinline__ float wave_sum(float v) {
    #pragma unroll
    for (int off = 32; off; off >>= 1) v += __shfl_xor(v, off, 64);
    return v;
}

__device__ __forceinline__ float hinner(float u, float v, float sgn) {
    return wave_sum(sgn * u * v);
}

__device__ __forceinline__ float cross_ratio(float r0, float r1, float r2, float r3, float sgn) {
    float A = hinner(r0, r2, sgn);
    float B = hinner(r1, r3, sgn);
    float C = hinner(r0, r3, sgn);
    float Dv = hinner(r1, r2, sgn);
    return (A * B) / (C * Dv + EPS);
}

__device__ __forceinline__ float restore_scale(float cr_i, float cr_c) {
    float ratio = cr_i / (cr_c + EPS);
    bool cond = (!__builtin_isnan(cr_c)) && (!__builtin_isnan(cr_i)) &&
                (fabsf(cr_c) > EPS) && (fabsf(cr_i) > EPS) && (ratio > EPS);
    float s = 1.0f;
    if (cond) {
        s = sqrtf(fabsf(ratio));
        if (!__builtin_isfinite(s)) s = 1.0f;
    }
    return s;
}

__device__ __forceinline__ unsigned short f2bf(float f) {
    unsigned u = __float_as_uint(f);
    unsigned r = (u + 0x7fffu + ((u >> 16) & 1u)) >> 16;
    return (unsigned short)r;
}

__device__ __forceinline__ float bf2f(unsigned short b) {
    return __uint_as_float(((unsigned)b) << 16);
}

__device__ __forceinline__ float bcast(float v, int lane) {
    return __int_as_float(__builtin_amdgcn_readlane(__float_as_int(v), lane));
}

// load one weight matrix as split-bf16 B fragments in VGPRs
__device__ __forceinline__ void load_bfrags(const float* __restrict__ W, int lane,
                                            short8 bhi[4][2], short8 blo[4][2]) {
    int c = lane & 15, q = lane >> 4;
    #pragma unroll
    for (int t = 0; t < 4; t++)
        #pragma unroll
        for (int h = 0; h < 2; h++) {
            short8 hi8, lo8;
            #pragma unroll
            for (int j = 0; j < 8; j++) {
                float w = W[(h * 32 + q * 8 + j) * DD + t * 16 + c];
                unsigned short hb = f2bf(w);
                float r = w - bf2f(hb);
                hi8[j] = (short)hb;
                lo8[j] = (short)f2bf(r);
            }
            bhi[t][h] = hi8;
            blo[t][h] = lo8;
        }
}

__device__ __forceinline__ void build_a8(const float av[8], short8& hi, short8& lo) {
    short8 h8, l8;
    #pragma unroll
    for (int j = 0; j < 8; j++) {
        unsigned short hb = f2bf(av[j]);
        float r = av[j] - bf2f(hb);
        h8[j] = (short)hb;
        l8[j] = (short)f2bf(r);
    }
    hi = h8;
    lo = l8;
}

__device__ __forceinline__ void build_a(const float* p, short8& hi, short8& lo) {
    float4 f0 = *(const float4*)p;
    float4 f1 = *(const float4*)(p + 4);
    float av[8] = {f0.x, f0.y, f0.z, f0.w, f1.x, f1.y, f1.z, f1.w};
    build_a8(av, hi, lo);
}

#define MFMA3R(cacc, ahi, alo, BH, BL, t, h)                                     \
    cacc = __builtin_amdgcn_mfma_f32_16x16x32_bf16(ahi, BH[t][h], cacc, 0, 0, 0); \
    cacc = __builtin_amdgcn_mfma_f32_16x16x32_bf16(alo, BH[t][h], cacc, 0, 0, 0); \
    cacc = __builtin_amdgcn_mfma_f32_16x16x32_bf16(ahi, BL[t][h], cacc, 0, 0, 0);

// fused: blocks [0,512) bucket-histogram; blocks [512,1536) layer0 MFMA.
__global__ __launch_bounds__(256, 3) void k_l0h(const float* __restrict__ x,
                                                const float* __restrict__ W0,
                                                const float* __restrict__ b0,
                                                unsigned short* __restrict__ h0b,
                                                const int* __restrict__ ei,
                                                int* __restrict__ bhist) {
    __shared__ int h[NBUCK];
    if (blockIdx.x < 512) {
        for (int i = threadIdx.x; i < NBUCK; i += 256) h[i] = 0;
        __syncthreads();
        int tid = blockIdx.x * 256 + threadIdx.x;
        int stride = 512 * 256;
        for (int e = tid; e < NEDGES; e += stride)
            atomicAdd(&h[(unsigned)ei[NEDGES + e] / BW], 1);
        __syncthreads();
        for (int i = threadIdx.x; i < NBUCK; i += 256)
            if (h[i]) atomicAdd(&bhist[i], h[i]);
        return;
    }
    int bid = blockIdx.x - 512;
    int lane = threadIdx.x & 63;
    int c = lane & 15, q = lane >> 4;
    short8 bhi[4][2], blo[4][2];
    load_bfrags(W0, lane, bhi, blo);
    float badd[4];
    #pragma unroll
    for (int t = 0; t < 4; t++) badd[t] = b0[t * 16 + c];
    int wid = (bid * 256 + threadIdx.x) >> 6;
    int nw = (1024 * 256) >> 6;
    for (int tile = wid; tile < NTILES; tile += nw) {
        int R = tile * 16;
        f32x4 cc[4] = {{0, 0, 0, 0}, {0, 0, 0, 0}, {0, 0, 0, 0}, {0, 0, 0, 0}};
        #pragma unroll
        for (int hh = 0; hh < 2; hh++) {
            short8 ahi, alo;
            build_a(x + ((size_t)(R + c) << 6) + hh * 32 + q * 8, ahi, alo);
            #pragma unroll
            for (int t = 0; t < 4; t++) { MFMA3R(cc[t], ahi, alo, bhi, blo, t, hh); }
        }
        float ss[4];
        #pragma unroll
        for (int r = 0; r < 4; r++) {
            #pragma unroll
            for (int t = 0; t < 4; t++) cc[t][r] += badd[t];
            ss[r] = cc[0][r] * cc[0][r] + cc[1][r] * cc[1][r] +
                    cc[2][r] * cc[2][r] + cc[3][r] * cc[3][r];
        }
        #pragma unroll
        for (int off = 1; off <= 8; off <<= 1) {
            #pragma unroll
            for (int r = 0; r < 4; r++) ss[r] += __shfl_xor(ss[r], off, 64);
        }
        #pragma unroll
        for (int r = 0; r < 4; r++) {
            float sc = 1.0f / (sqrtf(ss[r]) + EPS);
            int row = R + q * 4 + r;
            #pragma unroll
            for (int t = 0; t < 4; t++)
                h0b[(size_t)row * DD + t * 16 + c] = f2bf(cc[t][r] * sc);
        }
    }
}

// single block: exclusive scan of 1024 bucket counts -> bstart, gcur; init misc.
__global__ __launch_bounds__(NBUCK) void k_scan1024(const int* __restrict__ bhist,
                                                    int* __restrict__ bstart,
                                                    int* __restrict__ gcur,
                                                    int* __restrict__ scratch_cur) {
    __shared__ int s[NBUCK];
    int t = threadIdx.x;
    int v = bhist[t];
    s[t] = v;
    __syncthreads();
    for (int off = 1; off < NBUCK; off <<= 1) {
        int u = (t >= off) ? s[t - off] : 0;
        __syncthreads();
        s[t] += u;
        __syncthreads();
    }
    bstart[t] = s[t] - v;
    gcur[t] = s[t] - v;
    if (t == 0) scratch_cur[0] = 0;
}

// bin edges into per-bucket dense runs; also collect rows 0..3 neighbor lists.
__global__ __launch_bounds__(256) void k_bin(const int* __restrict__ ei,
                                             int* __restrict__ gcur,
                                             unsigned* __restrict__ colpack,
                                             int* __restrict__ cnt4,
                                             int* __restrict__ list4) {
    __shared__ unsigned stag[NBUCK * BIN_CAP];
    __shared__ int lcnt[NBUCK];
    int t = threadIdx.x;
    for (int i = t; i < NBUCK; i += 256) lcnt[i] = 0;
    __syncthreads();
    int lo = blockIdx.x * BIN_CHUNK;
    int hi = lo + BIN_CHUNK; if (hi > NEDGES) hi = NEDGES;
    for (int e = lo + t; e < hi; e += 256) {
        int d = ei[NEDGES + e];
        int s = ei[e];
        if ((unsigned)d < 4u) {
            int p = atomicAdd(&cnt4[d], 1);
            if (p < CAP4) list4[d * CAP4 + p] = s;
        }
        unsigned b = (unsigned)d / BW;
        unsigned dl = (unsigned)d - b * BW;
        unsigned pk = ((unsigned)s << 8) | dl;
        int slot = atomicAdd(&lcnt[b], 1);
        if (slot < BIN_CAP) {
            stag[b * BIN_CAP + slot] = pk;
        } else {
            colpack[atomicAdd(&gcur[b], 1)] = pk;
        }
    }
    __syncthreads();
    for (int b = t; b < NBUCK; b += 256) {
        int cnt = lcnt[b];
        if (cnt > BIN_CAP) cnt = BIN_CAP;
        if (cnt > 0) {
            int base = atomicAdd(&gcur[b], cnt);
            for (int i = 0; i < cnt; i++)
                colpack[base + i] = stag[b * BIN_CAP + i];
        }
    }
}

// blocks [0,NBUCK): counting-sort the bucket run into an LDS list, then the
// block's 4 waves gather-aggregate each node's neighbors from that list and
// write the fp32 mean to agg (=d_out). No sorted write-back, no row_ptr.
// block NBUCK: head — rows 0..3 full pipeline in fp32 -> scal.
__global__ __launch_bounds__(256, 4) void k_sortAggH(const unsigned* __restrict__ colpack,
                                                     const int* __restrict__ bstart,
                                                     const int* __restrict__ bhist,
                                                     const unsigned short* __restrict__ h0b,
                                                     float* __restrict__ agg,
                                                     int* __restrict__ scratch,
                                                     int* __restrict__ scratch_cur,
                                                     const float* __restrict__ x,
                                                     const float* __restrict__ W0,
                                                     const float* __restrict__ b0,
                                                     const int* __restrict__ cnt4,
                                                     const int* __restrict__ list4,
                                                     const float* __restrict__ Wm,
                                                     const float* __restrict__ bm,
                                                     const float* __restrict__ W1,
                                                     const float* __restrict__ b1,
                                                     float* __restrict__ scal) {
    __shared__ int lcol[SORT_CAP];   // 16 KB; head aliases its [4][64] arrays here
    __shared__ int cnt[BW];
    __shared__ int pre[BW];
    int t = threadIdx.x;
    if (blockIdx.x == NBUCK) {
        // ---- head (rows 0..3, fp32-exact) ----
        float* hs  = (float*)lcol;          // [4][64]
        float* h2s = hs + 4 * DD;
        float* frs = h2s + 4 * DD;
        int lane = t & 63;
        int w = t >> 6;
        float sgn = (lane == 63) ? -1.0f : 1.0f;
        float w0[DD];
        #pragma unroll
        for (int k = 0; k < DD; k++) w0[k] = W0[k * DD + lane];
        float b0v = b0[lane];
        auto h0row = [&](int r) -> float {
            float xv = x[(size_t)r * DD + lane];
            float acc = b0v;
            #pragma unroll
            for (int k = 0; k < DD; k++)
                acc = fmaf(bcast(xv, k), w0[k], acc);
            float n = sqrtf(wave_sum(acc * acc));
            return acc / (n + EPS);
        };
        hs[w * DD + lane] = h0row(w);
        int full = cnt4[w];
        int cl = full; if (cl > CAP4) cl = CAP4;
        float sum = 0.0f;
        for (int i = 0; i < cl; i++) sum += h0row(list4[w * CAP4 + i]);
        float av = sum / fmaxf((float)full, 1.0f);
        float acc = bm[lane];
        #pragma unroll
        for (int k = 0; k < DD; k++)
            acc = fmaf(bcast(av, k), Wm[k * DD + lane], acc);
        float n = sqrtf(wave_sum(acc * acc));
        h2s[w * DD + lane] = acc / (n + EPS);
        __syncthreads();
        float cr_init = cross_ratio(x[lane], x[DD + lane], x[2 * DD + lane], x[3 * DD + lane], sgn);
        float cr0 = cross_ratio(hs[lane], hs[DD + lane], hs[2 * DD + lane], hs[3 * DD + lane], sgn);
        float cr_cur = cross_ratio(h2s[lane], h2s[DD + lane], h2s[2 * DD + lane], h2s[3 * DD + lane], sgn);
        float s1 = restore_scale(cr0, cr_cur);
        float hv = h2s[w * DD + lane] * s1;
        float acc2 = b1[lane];
        #pragma unroll
        for (int k = 0; k < DD; k++)
            acc2 = fmaf(bcast(hv, k), W1[k * DD + lane], acc2);
        n = sqrtf(wave_sum(acc2 * acc2));
        frs[w * DD + lane] = fmaxf(acc2 / (n + EPS), 0.0f);
        __syncthreads();
        if (w == 0) {
            float cr2 = cross_ratio(frs[lane], frs[DD + lane], frs[2 * DD + lane], frs[3 * DD + lane], sgn);
            float s2 = restore_scale(cr_init, cr2);
            if (lane == 0) { scal[0] = s1; scal[1] = s2; }
        }
        return;
    }
    // ---- per-bucket: sort into LDS ----
    int b = blockIdx.x;
    int nlo = b * BW; if (nlo > NNODES) nlo = NNODES;
    int nhi = nlo + BW; if (nhi > NNODES) nhi = NNODES;
    int nodes = nhi - nlo;
    int base = bstart[b];
    int n = bhist[b];
    for (int i = t; i < BW; i += 256) cnt[i] = 0;
    __syncthreads();
    bool inLds = (n <= SORT_CAP);
    if (inLds) {
        unsigned ent[SORT_CAP / 256];
        int c = 0;
        for (int i = t; i < n; i += 256) {
            ent[c] = colpack[base + i];
            atomicAdd(&cnt[ent[c] & 255u], 1);
            c++;
        }
        __syncthreads();
        if (t == 0) {
            int s = 0;
            for (int i = 0; i < BW; i++) { pre[i] = s; s += cnt[i]; }
        }
        __syncthreads();
        for (int i = t; i < BW; i += 256) cnt[i] = pre[i];
        __syncthreads();
        for (int j = 0; j < c; j++) {
            int pos = atomicAdd(&cnt[ent[j] & 255u], 1);
            lcol[pos] = (int)(ent[j] >> 8);
        }
    } else {
        // fallback (statistically never at mean bucket 1562): sort via global scratch
        int sb = 0;
        if (t == 0) sb = atomicAdd(scratch_cur, n);
        sb = __shfl(sb, 0, 64);
        sb = __builtin_amdgcn_readfirstlane(sb);
        for (int i = t; i < n; i += 256) {
            unsigned pk = colpack[base + i];
            atomicAdd(&cnt[pk & 255u], 1);
            scratch[sb + i] = (int)pk;
        }
        __syncthreads();
        if (t == 0) {
            int s = 0;
            for (int i = 0; i < BW; i++) { pre[i] = s; s += cnt[i]; }
        }
        __syncthreads();
        for (int i = t; i < BW; i += 256) cnt[i] = pre[i];
        __syncthreads();
        // place sorted into the tail half of scratch region? reuse lcol not possible;
        // scatter into scratch[sb + n + pos] requires 2n <= scratch space — instead
        // overwrite colpack is not allowed (const). Use scratch twice: read pk then
        // write sorted src into scratch[sb + pos] is unsafe in-place; two-phase:
        // (a) read all pk into registers first (n may exceed reg budget) -> chunked:
        for (int i = t; i < n; i += 256) {
            unsigned pk = (unsigned)scratch[sb + i];   // all reads of chunk i done
            int pos = atomicAdd(&cnt[pk & 255u], 1);
            // write into lcol when pos fits, else leave: n > SORT_CAP can't fit LDS;
            // store sorted value back into scratch offset by +pos with marker-free
            // second array region at sb (in-place hazard): acceptable because each
            // slot is written exactly once and read slots i are consumed before any
            // write to them can occur only if pos >= i for all — not guaranteed.
            // Safe route: write to global agg staging is unavailable; instead stash
            // sorted into colpack's own window via const_cast (no other reader).
            ((unsigned*)colpack)[base + pos] = pk >> 8;
        }
    }
    __syncthreads();
    // ---- gather-aggregate from the sorted list ----
    int wv = t >> 6, lane = t & 63;
    int q = lane & 7, g = lane >> 3;
    for (int dl = wv; dl < nodes; dl += 4) {
        int start = pre[dl];
        int end = cnt[dl];   // after placement, cnt[dl] = pre[dl] + degree
        float s[8] = {0, 0, 0, 0, 0, 0, 0, 0};
        for (int j0 = start; j0 < end; j0 += 8) {
            int e = j0 + g;
            bool val = e < end;
            int src = 0;
            if (val) src = inLds ? lcol[e] : (int)colpack[base + e];
            us8 u = *(const us8*)(h0b + (size_t)src * DD + q * 8);
            float f = val ? 1.0f : 0.0f;
            #pragma unroll
            for (int i = 0; i < 8; i++)
                s[i] = fmaf(f, bf2f(u[i]), s[i]);
        }
        #pragma unroll
        for (int i = 0; i < 8; i++) {
            s[i] += __shfl_xor(s[i], 8, 64);
            s[i] += __shfl_xor(s[i], 16, 64);
            s[i] += __shfl_xor(s[i], 32, 64);
        }
        if (g == 0) {
            float inv = 1.0f / fmaxf((float)(end - start), 1.0f);
            float4* dst = (float4*)(agg + (size_t)(nlo + dl) * DD + q * 8);
            float4 o0 = {s[0] * inv, s[1] * inv, s[2] * inv, s[3] * inv};
            float4 o1 = {s[4] * inv, s[5] * inv, s[6] * inv, s[7] * inv};
            dst[0] = o0;
            dst[1] = o1;
        }
    }
}

// both GEMMs fused, in place on `data` (=agg):
// H = s1*normalize(data@Wm+bm); out = s2*relu(normalize(H@W1+b1)).
__global__ __launch_bounds__(256, 2) void k_gemm2(float* data,
                                                  const float* __restrict__ Wm,
                                                  const float* __restrict__ bm,
                                                  const float* __restrict__ W1,
                                                  const float* __restrict__ b1,
                                                  const float* __restrict__ scal) {
    __shared__ float tsm[4][16 * TSTR];
    int tid = threadIdx.x;
    int wv = tid >> 6, lane = tid & 63;
    int c = lane & 15, q = lane >> 4;
    short8 bhiM[4][2], bloM[4][2], bhi1[4][2], blo1[4][2];
    load_bfrags(Wm, lane, bhiM, bloM);
    load_bfrags(W1, lane, bhi1, blo1);
    float bmv[4], b1v[4];
    #pragma unroll
    for (int t = 0; t < 4; t++) { bmv[t] = bm[t * 16 + c]; b1v[t] = b1[t * 16 + c]; }
    float s1 = scal[0], s2 = scal[1];
    int wid = (blockIdx.x * 256 + tid) >> 6;
    int nw = (gridDim.x * 256) >> 6;
    for (int tile = wid; tile < NTILES; tile += nw) {
        int R = tile * 16;
        f32x4 cc[4] = {{0, 0, 0, 0}, {0, 0, 0, 0}, {0, 0, 0, 0}, {0, 0, 0, 0}};
        #pragma unroll
        for (int hh = 0; hh < 2; hh++) {
            short8 ahi, alo;
            build_a(data + ((size_t)(R + c) << 6) + hh * 32 + q * 8, ahi, alo);
            #pragma unroll
            for (int t = 0; t < 4; t++) { MFMA3R(cc[t], ahi, alo, bhiM, bloM, t, hh); }
        }
        float ss[4];
        #pragma unroll
        for (int r = 0; r < 4; r++) {
            #pragma unroll
            for (int t = 0; t < 4; t++) cc[t][r] += bmv[t];
            ss[r] = cc[0][r] * cc[0][r] + cc[1][r] * cc[1][r] +
                    cc[2][r] * cc[2][r] + cc[3][r] * cc[3][r];
        }
        #pragma unroll
        for (int off = 1; off <= 8; off <<= 1) {
            #pragma unroll
            for (int r = 0; r < 4; r++) ss[r] += __shfl_xor(ss[r], off, 64);
        }
        #pragma unroll
        for (int r = 0; r < 4; r++) {
            float sc = s1 / (sqrtf(ss[r]) + EPS);
            #pragma unroll
            for (int t = 0; t < 4; t++)
                tsm[wv][(q * 4 + r) * TSTR + t * 16 + c] = cc[t][r] * sc;
        }
        f32x4 c2[4] = {{0, 0, 0, 0}, {0, 0, 0, 0}, {0, 0, 0, 0}, {0, 0, 0, 0}};
        #pragma unroll
        for (int hh = 0; hh < 2; hh++) {
            const float* p = &tsm[wv][c * TSTR + hh * 32 + q * 8];
            float av[8];
            #pragma unroll
            for (int j = 0; j < 8; j++) av[j] = p[j];
            short8 ahi, alo;
            build_a8(av, ahi, alo);
            #pragma unroll
            for (int t = 0; t < 4; t++) { MFMA3R(c2[t], ahi, alo, bhi1, blo1, t, hh); }
        }
        #pragma unroll
        for (int r = 0; r < 4; r++) {
            #pragma unroll
            for (int t = 0; t < 4; t++) c2[t][r] += b1v[t];
            ss[r] = c2[0][r] * c2[0][r] + c2[1][r] * c2[1][r] +
                    c2[2][r] * c2[2][r] + c2[3][r] * c2[3][r];
        }
        #pragma unroll
        for (int off = 1; off <= 8; off <<= 1) {
            #pragma unroll
            for (int r = 0; r < 4; r++) ss[r] += __shfl_xor(ss[r], off, 64);
        }
        #pragma unroll
        for (int r = 0; r < 4; r++) {
            float sc = 1.0f / (sqrtf(ss[r]) + EPS);
            int row = R + q * 4 + r;
            #pragma unroll
            for (int t = 0; t < 4; t++)
                data[(size_t)row * DD + t * 16 + c] = fmaxf(c2[t][r] * sc, 0.0f) * s2;
        }
    }
}

extern "C" void kernel_launch(void* const* d_in, const int* in_sizes, int n_in,
                              void* d_out, int out_size, void* d_ws, size_t ws_size,
                              hipStream_t stream) {
    const float* x  = (const float*)d_in[0];
    const int*   ei = (const int*)d_in[1];
    const float* W0 = (const float*)d_in[2];
    const float* b0 = (const float*)d_in[3];
    const float* Wm = (const float*)d_in[4];
    const float* bm = (const float*)d_in[5];
    const float* W1 = (const float*)d_in[6];
    const float* b1 = (const float*)d_in[7];
    float* out = (float*)d_out;

    // ws layout (~19.7 MB)
    unsigned short* h0b = (unsigned short*)d_ws;                 // N*64 bf16 = 12.8 MB
    int* scratch = (int*)(h0b + (size_t)NNODES * DD);            // N (sort overflow scratch)
    unsigned* colpack = (unsigned*)(scratch + NNODES);           // E = 6.4 MB
    int* bhist  = (int*)(colpack + NEDGES);                      // 1024
    int* cnt4   = bhist + NBUCK;                                 // 4
    int* bstart = cnt4 + 4;                                      // 1024
    int* gcur   = bstart + NBUCK;                                // 1024
    int* scur   = gcur + NBUCK;                                  // 1
    int* list4  = scur + 1;                                      // 4*512
    float* scal = (float*)(list4 + 4 * CAP4);                    // 2

    (void)hipMemsetAsync(bhist, 0, (NBUCK + 4) * sizeof(int), stream);  // bhist + cnt4

    k_l0h     <<<1536, 256, 0, stream>>>(x, W0, b0, h0b, ei, bhist);
    k_scan1024<<<1, NBUCK, 0, stream>>>(bhist, bstart, gcur, scur);
    k_bin     <<<BIN_BLOCKS, 256, 0, stream>>>(ei, gcur, colpack, cnt4, list4);
    k_sortAggH<<<NBUCK + 1, 256, 0, stream>>>(colpack, bstart, bhist, h0b, out, scratch, scur,
                                              x, W0, b0, cnt4, list4, Wm, bm, W1, b1, scal);
    k_gemm2   <<<512, 256, 0, stream>>>(out, Wm, bm, W1, b1, scal);
}